// Round 15
// baseline (108.845 us; speedup 1.0000x reference)
//
#include <hip/hip_runtime.h>
#include <hip/hip_bf16.h>
#include <hip/hip_fp8.h>

typedef float f32x4 __attribute__((ext_vector_type(4)));
typedef long long i64;
typedef i64 i64x2 __attribute__((ext_vector_type(2)));

#define N_SPK 1024
#define M_UTT 40
#define D_FEAT 768
#define NROWS (N_SPK * M_UTT)
#define LOG2E 1.44269504088896340736f
#define LN2   0.69314718055994530942f

#define BM 160             // 40960/160 = 256 row tiles; x8 col tiles = 2048 = EXACTLY 2 generations at 4 blocks/CU
#define BN 128
#define BKB 64             // fp8 elems (=bytes) per K-tile
#define KT (D_FEAT / BKB)  // 12
#define ROWB 768           // bytes per fp8 source row

#define ABYTES 10240       // A region: 80 LDS rows x 128B (160 src rows pair-packed)
#define TILEB  18432       // A (10240) + B (8192)
#define SCRATCH 36864      // 2KB dummy-GLD sink (waves 2-3 of A-chunk2)

// xn stored *8, cc stored *8  ->  acc = 64 * sim
#define INV_SS (1.0f / 64.0f)
#define SCL 8.0f

__device__ __forceinline__ unsigned char to_fp8(float v) {
  __hip_fp8_e4m3 t(v);
  return (unsigned char)t.__x;
}

// Feature permutation (identical for xn and cc -> dot product invariant):
// within each 64-byte k-group, 16B slot m = orig k {8m..8m+7} ++ {32+8m..32+8m+7},
// so ONE ds_read_b128 yields both MFMA k-substeps (lo = sub0, hi = sub1).
// stored_j(j) = ((j>>3)&3)*16 + (j&7) + ((j>>5)<<3).
// 4-aligned k quads stay contiguous under the permutation -> uchar4 stores valid.
__device__ __forceinline__ int perm4base(int k0) {  // k0 % 4 == 0
  const int b = k0 & 63;
  return (k0 & ~63) + ((b >> 3) & 3) * 16 + (b & 7) + ((b >> 5) << 3);
}

// ---------------- Kernel 1: fused L2-normalize + centroid, float4 loads (R14-verified) ----------------
__global__ __launch_bounds__(256) void k_norm_cent(const float* __restrict__ x,
                                                   unsigned char* __restrict__ xn,
                                                   unsigned char* __restrict__ cc) {
  const int n = blockIdx.x, t = threadIdx.x;
  const int lane = t & 63, wv = t >> 6;
  const float4* xb4 = (const float4*)(x + (size_t)n * (M_UTT * D_FEAT));
  unsigned char* ob = xn + (size_t)n * (M_UTT * D_FEAT);

  __shared__ float bins[2][4][3];    // [parity][row][slot]
  __shared__ float cl[4][192][4];    // 12KB: [owner][col4][comp]

  int o_[3], c4_[3], soff_[3];
#pragma unroll
  for (int q = 0; q < 3; ++q) {
    const int f = q * 256 + t;
    o_[q]  = f / 192;
    c4_[q] = f % 192;
    soff_[q] = perm4base(4 * c4_[q]);
  }

  float cacc[3][4];
#pragma unroll
  for (int q = 0; q < 3; ++q)
#pragma unroll
    for (int c = 0; c < 4; ++c) cacc[q][c] = 0.f;

  for (int g = 0; g < M_UTT / 4; ++g) {
    const int p = g & 1;
    float4 v[3];
#pragma unroll
    for (int q = 0; q < 3; ++q) v[q] = xb4[g * 768 + q * 256 + t];
    float ss[3];
#pragma unroll
    for (int q = 0; q < 3; ++q)
      ss[q] = v[q].x * v[q].x + v[q].y * v[q].y + v[q].z * v[q].z + v[q].w * v[q].w;
#pragma unroll
    for (int d = 1; d < 64; d <<= 1) {
      ss[0] += __shfl_xor(ss[0], d, 64);
      ss[1] += __shfl_xor(ss[1], d, 64);
      ss[2] += __shfl_xor(ss[2], d, 64);
    }
    if (lane == 0) {
#pragma unroll
      for (int q = 0; q < 3; ++q) {
        const int idx = 4 * q + wv;
        bins[p][idx / 3][idx % 3] = ss[q];
      }
    }
    __syncthreads();  // parity dbuf: bins[p] rewritten 2 syncs later -> safe
#pragma unroll
    for (int q = 0; q < 3; ++q) {
      const int o = o_[q];
      const float tot = bins[p][o][0] + bins[p][o][1] + bins[p][o][2];
      const float iv = 1.0f / fmaxf(sqrtf(tot), 1e-12f);
      const float w0 = v[q].x * iv, w1 = v[q].y * iv, w2 = v[q].z * iv, w3 = v[q].w * iv;
      cacc[q][0] += w0; cacc[q][1] += w1; cacc[q][2] += w2; cacc[q][3] += w3;
      uchar4 u;
      u.x = to_fp8(w0 * SCL); u.y = to_fp8(w1 * SCL);
      u.z = to_fp8(w2 * SCL); u.w = to_fp8(w3 * SCL);
      *(uchar4*)(ob + (size_t)(4 * g + o) * D_FEAT + soff_[q]) = u;
    }
  }

#pragma unroll
  for (int q = 0; q < 3; ++q) {
#pragma unroll
    for (int c = 0; c < 4; ++c) cl[o_[q]][c4_[q]][c] = cacc[q][c];
  }
  __syncthreads();
  if (t < 192) {
    float s[4];
#pragma unroll
    for (int c = 0; c < 4; ++c)
      s[c] = cl[0][t][c] + cl[1][t][c] + cl[2][t][c] + cl[3][t][c];
    const float sc = SCL / (float)M_UTT;
    uchar4 u;
    u.x = to_fp8(s[0] * sc); u.y = to_fp8(s[1] * sc);
    u.z = to_fp8(s[2] * sc); u.w = to_fp8(s[3] * sc);
    *(uchar4*)(cc + (size_t)n * D_FEAT + perm4base(4 * t)) = u;
  }
}

// ---------------- Kernel 2: 160x128 fp8 GEMM (R8 structure, generation-exact grid) ----------------
// 256 thr = 4 waves (2x2 of 80x64; 5x4 frags of 16x16x32 fp8; 40 MFMA per K-tile).
// LDS: dbuf x 18KB (A 10240 + B 8192) + 2KB scratch; 64B src rows pair-packed into
// 128B LDS rows, phys = logical ^ ((R&7)<<4) (R8's measured-0-conflict scheme).
// STAGE = 5 GLD/wave uniform: A c0,c1 (rows 0-127), A c2 (rows 128-159 via tid<128;
// waves 2-3 issue a dummy GLD into scratch so outstanding counts stay uniform), B c0,c1.
// Loop: stage k+1 -> vmcnt(5) [= tile k landed, k+1's 5 in flight] -> barrier ->
// 9x ds_read_b128 + 40 MFMA -> lgkmcnt(0) -> barrier. Never vmcnt(0) mid-loop.
// Grid 2048 at 4 blocks/CU = EXACTLY 2 generations (fixes R8's 2.5->3 quantized tail).
#define GLD(g, l) __builtin_amdgcn_global_load_lds( \
    (const __attribute__((address_space(1))) unsigned int*)(g), \
    (__attribute__((address_space(3))) unsigned int*)(l), 16, 0, 0)

__global__ __launch_bounds__(256, 4) void k_gemm_part(
    const unsigned char* __restrict__ XN, const unsigned char* __restrict__ CC,
    const float* __restrict__ wp, const float* __restrict__ bp,
    float2* __restrict__ ppart, float* __restrict__ picked2) {

  __shared__ __align__(16) char smem[38912];

  const int tid  = threadIdx.x;
  const int wave = tid >> 6, lane = tid & 63;
  const int l16  = lane & 15, lg = lane >> 4;
  const int wr   = wave >> 1, wc = wave & 1;

  // bijective XCD swizzle: 2048 = 8 XCD x 256; a row-tile's 8 col-blocks share one XCD
  const int bid = blockIdx.x;
  const int xcd = bid & 7;
  const int idx = bid >> 3;              // 0..255
  const int rb  = xcd * 32 + (idx >> 3); // 0..255
  const int cb  = idx & 7;               // 0..7
  const int rowbase = rb * BM;
  const int colbase = cb * BN;

  // staging source mapping (inverse of pair-packed swizzle):
  // thread t fills LDS bytes o = chunk_base + t*16 (chunks of 32 LDS rows);
  // LDS-row-in-chunk = t>>3, logical_inner = ((t&7)*16) ^ (((t>>3)&7)<<4);
  // src_row = 2*(t>>3) + (li>>6), src k-byte = li&63.
  const int li   = ((tid & 7) * 16) ^ (((tid >> 3) & 7) << 4);
  const int row0 = 2 * (tid >> 3) + (li >> 6);   // 0..63
  const int kb   = li & 63;
  const int t16  = tid * 16;
  const unsigned char* gA = XN + (size_t)(rowbase + row0) * ROWB + kb;
  const unsigned char* gB = CC + (size_t)(colbase + row0) * ROWB + kb;
  // A chunk2 (src rows 128-159): tid<128 -> real; waves 2-3 -> dummy into scratch
  char* c2dst = (tid < 128) ? (char*)nullptr : nullptr;  // computed per STAGE below

  // fragment ds_read_b128 offsets: A row r = wr*80 + i*16 + l16 -> LDS-row wr*40 + i*8
  // + (l16>>1); B col c = wc*64 + j*16 + l16 -> LDS-row wc*32 + j*8 + (l16>>1);
  // inner logical = ((l16&1)<<6)|(lg<<4), phys = logical ^ (((l16>>1)&7)<<4)
  const int xr  = ((l16 >> 1) & 7) << 4;
  const int in0 = ((((l16 & 1) << 6) | (lg << 4)) ^ xr);
  int aoff[5], boff[4];
#pragma unroll
  for (int i = 0; i < 5; ++i)
    aoff[i] = (wr * 40 + i * 8 + (l16 >> 1)) * 128 + in0;
#pragma unroll
  for (int jj = 0; jj < 4; ++jj)
    boff[jj] = ABYTES + (wc * 32 + jj * 8 + (l16 >> 1)) * 128 + in0;

  f32x4 acc[5][4];
#pragma unroll
  for (int i = 0; i < 5; ++i)
#pragma unroll
    for (int jj = 0; jj < 4; ++jj) acc[i][jj] = (f32x4){0.f, 0.f, 0.f, 0.f};

  auto STAGE = [&](int buf, int koff) {
    char* sb = smem + buf * TILEB;
    GLD(gA + koff,              sb + t16);                       // A rows 0-63
    GLD(gA + 64 * ROWB + koff,  sb + 4096 + t16);                // A rows 64-127
    // A rows 128-159 (2KB): waves 0-1 real, waves 2-3 dummy into scratch (uniform count)
    {
      const unsigned char* src = (tid < 128) ? (gA + 128 * ROWB + koff) : (gA + koff);
      char* dst = (tid < 128) ? (sb + 8192 + t16) : (smem + SCRATCH + (t16 - 2048));
      GLD(src, dst);
    }
    GLD(gB + koff,              sb + ABYTES + t16);              // B rows 0-63
    GLD(gB + 64 * ROWB + koff,  sb + ABYTES + 4096 + t16);       // B rows 64-127
  };

  STAGE(0, 0);  // prologue: tile 0 (5 loads outstanding)

  for (int k = 0; k < KT; ++k) {
    const char* bb = smem + (k & 1) * TILEB;
    if (k + 1 < KT) {
      STAGE((k + 1) & 1, (k + 1) * BKB);
      asm volatile("s_waitcnt vmcnt(5)" ::: "memory");  // tile k landed; k+1's 5 in flight
    } else {
      asm volatile("s_waitcnt vmcnt(0)" ::: "memory");
    }
    __builtin_amdgcn_s_barrier();

    i64x2 bv[4];
#pragma unroll
    for (int jj = 0; jj < 4; ++jj) bv[jj] = *(const i64x2*)(bb + boff[jj]);
    __builtin_amdgcn_s_setprio(1);
#pragma unroll
    for (int i = 0; i < 5; ++i) {
      const i64x2 av = *(const i64x2*)(bb + aoff[i]);
#pragma unroll
      for (int jj = 0; jj < 4; ++jj) {
        acc[i][jj] = __builtin_amdgcn_mfma_f32_16x16x32_fp8_fp8(av[0], bv[jj][0], acc[i][jj], 0, 0, 0);
        acc[i][jj] = __builtin_amdgcn_mfma_f32_16x16x32_fp8_fp8(av[1], bv[jj][1], acc[i][jj], 0, 0, 0);
      }
    }
    __builtin_amdgcn_s_setprio(0);
    asm volatile("s_waitcnt lgkmcnt(0)" ::: "memory");  // reads retired before overwrite
    __builtin_amdgcn_s_barrier();
  }

  // ---- epilogue: unscale + diag fixup + per-row (max, sumexp) base-2 partials ----
  const float ws2 = wp[0] * LOG2E;
  const float b2  = bp[0] * LOG2E;
  float2* red = (float2*)smem;  // [160][2] float2 = 2.5KB in buf0; last tile read buf1 -> safe

#pragma unroll
  for (int i = 0; i < 5; ++i) {
#pragma unroll
    for (int rr = 0; rr < 4; ++rr) {
      const int lrow = wr * 80 + i * 16 + lg * 4 + rr;  // 0..159
      const int R = rowbase + lrow;
      const int n = R / M_UTT;
      float l2[4];
#pragma unroll
      for (int jj = 0; jj < 4; ++jj) {
        float sim = acc[i][jj][rr] * INV_SS;
        const int gc = colbase + wc * 64 + jj * 16 + l16;
        if (gc == n) {
          sim = (40.f * sim - 1.f) * (1.f / 39.f);  // exclusive centroid; ||xn|| = 1
          picked2[R] = fmaf(ws2, sim, b2);
        }
        l2[jj] = fmaf(ws2, sim, b2);
      }
      float mx = fmaxf(fmaxf(l2[0], l2[1]), fmaxf(l2[2], l2[3]));
#pragma unroll
      for (int d = 1; d < 16; d <<= 1) mx = fmaxf(mx, __shfl_xor(mx, d, 64));
      float s = exp2f(l2[0] - mx) + exp2f(l2[1] - mx) +
                exp2f(l2[2] - mx) + exp2f(l2[3] - mx);
#pragma unroll
      for (int d = 1; d < 16; d <<= 1) s += __shfl_xor(s, d, 64);
      if (l16 == 0) red[lrow * 2 + wc] = make_float2(mx, s);
    }
  }
  __syncthreads();
  if (tid < 160) {
    const float2 p0 = red[tid * 2 + 0];
    const float2 p1 = red[tid * 2 + 1];
    const float m2 = fmaxf(p0.x, p1.x);
    const float ss = p0.y * exp2f(p0.x - m2) + p1.y * exp2f(p1.x - m2);
    ppart[(size_t)(rowbase + tid) * 8 + cb] = make_float2(m2, ss);
  }
}

// ---------------- Kernel 3: combine partials -> row loss + per-block sum ----------------
__global__ __launch_bounds__(256) void k_combine(const float2* __restrict__ pp,
                                                 const float* __restrict__ picked2,
                                                 double* __restrict__ partial) {
  const int t = threadIdx.x;
  const int R = blockIdx.x * 256 + t;
  const float2* p = pp + (size_t)R * 8;
  float2 v[8];
#pragma unroll
  for (int j = 0; j < 8; ++j) v[j] = p[j];
  float m2 = v[0].x;
#pragma unroll
  for (int j = 1; j < 8; ++j) m2 = fmaxf(m2, v[j].x);
  float s = 0.f;
#pragma unroll
  for (int j = 0; j < 8; ++j) s += v[j].y * exp2f(v[j].x - m2);
  const float lse2 = m2 + log2f(s);
  const float rl = (lse2 - picked2[R]) * LN2;

  __shared__ double sm[256];
  sm[t] = (double)rl;
  __syncthreads();
  for (int off = 128; off > 0; off >>= 1) {
    if (t < off) sm[t] += sm[t + off];
    __syncthreads();
  }
  if (t == 0) partial[blockIdx.x] = sm[0];
}

// ---------------- Kernel 4: final mean over 160 block partials ----------------
__global__ __launch_bounds__(256) void k_reduce(const double* __restrict__ partial,
                                                float* __restrict__ out) {
  const int t = threadIdx.x;
  __shared__ double sm[256];
  sm[t] = (t < NROWS / 256) ? partial[t] : 0.0;
  __syncthreads();
  for (int off = 128; off > 0; off >>= 1) {
    if (t < off) sm[t] += sm[t + off];
    __syncthreads();
  }
  if (t == 0) out[0] = (float)(sm[0] / (double)NROWS);
}

extern "C" void kernel_launch(void* const* d_in, const int* in_sizes, int n_in,
                              void* d_out, int out_size, void* d_ws, size_t ws_size,
                              hipStream_t stream) {
  const float* x = (const float*)d_in[0];
  const float* w = (const float*)d_in[1];
  const float* b = (const float*)d_in[2];
  char* ws = (char*)d_ws;
  size_t off = 0;
  unsigned char* xn = (unsigned char*)(ws + off); off += (size_t)NROWS * D_FEAT;
  unsigned char* cc = (unsigned char*)(ws + off); off += (size_t)N_SPK * D_FEAT;
  off = (off + 255) & ~(size_t)255;
  float2* ppart   = (float2*)(ws + off); off += (size_t)NROWS * 8 * sizeof(float2);
  float* picked2  = (float*)(ws + off);  off += (size_t)NROWS * sizeof(float);
  off = (off + 255) & ~(size_t)255;
  double* partial = (double*)(ws + off); off += (size_t)(NROWS / 256) * sizeof(double);
  float* out = (float*)d_out;

  k_norm_cent<<<N_SPK, 256, 0, stream>>>(x, xn, cc);
  k_gemm_part<<<(NROWS / BM) * (N_SPK / BN), 256, 0, stream>>>(xn, cc, w, b, ppart, picked2);
  k_combine<<<NROWS / 256, 256, 0, stream>>>(ppart, picked2, partial);
  k_reduce<<<1, 256, 0, stream>>>(partial, out);
}

// Round 16
// 95.177 us; speedup vs baseline: 1.1436x; 1.1436x over previous
//
#include <hip/hip_runtime.h>
#include <hip/hip_bf16.h>
#include <hip/hip_fp8.h>

typedef float f32x4 __attribute__((ext_vector_type(4)));
typedef long long i64;
typedef i64 i64x2 __attribute__((ext_vector_type(2)));

#define N_SPK 1024
#define M_UTT 40
#define D_FEAT 768
#define NROWS (N_SPK * M_UTT)
#define LOG2E 1.44269504088896340736f
#define LN2   0.69314718055994530942f

#define BM 128
#define BN 128
#define BKB 64             // fp8 elems (=bytes) per K-tile
#define KT (D_FEAT / BKB)  // 12
#define ROWB 768           // bytes per fp8 source row

// xn stored *8, cc stored *8  ->  acc = 64 * sim
#define INV_SS (1.0f / 64.0f)
#define SCL 8.0f

__device__ __forceinline__ unsigned char to_fp8(float v) {
  __hip_fp8_e4m3 t(v);
  return (unsigned char)t.__x;
}

// Feature permutation (identical for xn and cc -> dot product invariant):
// within each 64-byte k-group, 16B slot m = orig k {8m..8m+7} ++ {32+8m..32+8m+7},
// so ONE ds_read_b128 yields both MFMA k-substeps (lo = sub0, hi = sub1).
// stored_j(j) = ((j>>3)&3)*16 + (j&7) + ((j>>5)<<3
// For a 4-aligned k base b (b%4==0) the 4 bytes b..b+3 stay CONSECUTIVE after the
// permutation (only j&7 varies, contiguously) -> uchar4 stores are valid.
__device__ __forceinline__ int perm4base(int k0) {  // k0 % 4 == 0
  const int b = k0 & 63;
  return (k0 & ~63) + ((b >> 3) & 3) * 16 + (b & 7) + ((b >> 5) << 3);
}

// ---------------- Kernel 1: fused L2-normalize + centroid, float4 loads (G13) ----------------
// 256 thr, one speaker; 4 rows per group (10 groups). Flat float4 index f = q*256 + t
// (q=0..2) over the 4-row span: row o = f/192 is WAVE-UNIFORM (boundaries at multiples
// of 64). Wave-contrib idx = 4q+wv -> row (4q+wv)/3, slot (4q+wv)%3 (3 waves per row).
// Centroid partials: (o = f/192, c4 = f%192) is a bijection over 4x192 slots ->
// direct LDS stores, no zero-init, no atomics.
__global__ __launch_bounds__(256) void k_norm_cent(const float* __restrict__ x,
                                                   unsigned char* __restrict__ xn,
                                                   unsigned char* __restrict__ cc) {
  const int n = blockIdx.x, t = threadIdx.x;
  const int lane = t & 63, wv = t >> 6;
  const float4* xb4 = (const float4*)(x + (size_t)n * (M_UTT * D_FEAT));
  unsigned char* ob = xn + (size_t)n * (M_UTT * D_FEAT);

  __shared__ float bins[2][4][3];    // [parity][row][slot]
  __shared__ float cl[4][192][4];    // 12KB: [owner][col4][comp]

  int o_[3], c4_[3], soff_[3];
#pragma unroll
  for (int q = 0; q < 3; ++q) {
    const int f = q * 256 + t;
    o_[q]  = f / 192;
    c4_[q] = f % 192;
    soff_[q] = perm4base(4 * c4_[q]);
  }

  float cacc[3][4];
#pragma unroll
  for (int q = 0; q < 3; ++q)
#pragma unroll
    for (int c = 0; c < 4; ++c) cacc[q][c] = 0.f;

  for (int g = 0; g < M_UTT / 4; ++g) {
    const int p = g & 1;
    float4 v[3];
#pragma unroll
    for (int q = 0; q < 3; ++q) v[q] = xb4[g * 768 + q * 256 + t];
    float ss[3];
#pragma unroll
    for (int q = 0; q < 3; ++q)
      ss[q] = v[q].x * v[q].x + v[q].y * v[q].y + v[q].z * v[q].z + v[q].w * v[q].w;
#pragma unroll
    for (int d = 1; d < 64; d <<= 1) {
      ss[0] += __shfl_xor(ss[0], d, 64);
      ss[1] += __shfl_xor(ss[1], d, 64);
      ss[2] += __shfl_xor(ss[2], d, 64);
    }
    if (lane == 0) {
#pragma unroll
      for (int q = 0; q < 3; ++q) {
        const int idx = 4 * q + wv;
        bins[p][idx / 3][idx % 3] = ss[q];
      }
    }
    __syncthreads();  // parity dbuf: bins[p] rewritten 2 syncs later -> safe
#pragma unroll
    for (int q = 0; q < 3; ++q) {
      const int o = o_[q];
      const float tot = bins[p][o][0] + bins[p][o][1] + bins[p][o][2];
      const float iv = 1.0f / fmaxf(sqrtf(tot), 1e-12f);
      const float w0 = v[q].x * iv, w1 = v[q].y * iv, w2 = v[q].z * iv, w3 = v[q].w * iv;
      cacc[q][0] += w0; cacc[q][1] += w1; cacc[q][2] += w2; cacc[q][3] += w3;
      uchar4 u;
      u.x = to_fp8(w0 * SCL); u.y = to_fp8(w1 * SCL);
      u.z = to_fp8(w2 * SCL); u.w = to_fp8(w3 * SCL);
      *(uchar4*)(ob + (size_t)(4 * g + o) * D_FEAT + soff_[q]) = u;
    }
  }

  // centroid merge: direct injective stores, then 192 threads finalize
#pragma unroll
  for (int q = 0; q < 3; ++q) {
#pragma unroll
    for (int c = 0; c < 4; ++c) cl[o_[q]][c4_[q]][c] = cacc[q][c];
  }
  __syncthreads();
  if (t < 192) {
    float s[4];
#pragma unroll
    for (int c = 0; c < 4; ++c)
      s[c] = cl[0][t][c] + cl[1][t][c] + cl[2][t][c] + cl[3][t][c];
    const float sc = SCL / (float)M_UTT;
    uchar4 u;
    u.x = to_fp8(s[0] * sc); u.y = to_fp8(s[1] * sc);
    u.z = to_fp8(s[2] * sc); u.w = to_fp8(s[3] * sc);
    *(uchar4*)(cc + (size_t)n * D_FEAT + perm4base(4 * t)) = u;
  }
}

// ---------------- Kernel 2: 128x128 fp8 GEMM (verified R8 kernel, verbatim) ----------------
// 256 thr = 4 waves (2x2 of 64x64; 4x4 frags of 16x16x32 fp8; 32 MFMA per K-tile).
// LDS 32KB dbuf (16KB/tile): 64B src rows pair-packed into 128B LDS rows, XOR swizzle
// physical_inner = logical ^ ((R&7)<<4). Frag read = ONE ds_read_b128 per (frag,row)
// (permuted k-layout packs both substeps) -- measured 0 bank conflicts.
// Loop: stage k+1 -> vmcnt(4) -> barrier -> 8x ds_read_b128 + 32 MFMA -> lgkmcnt(0)
// -> barrier. Never vmcnt(0) mid-loop. launch_bounds(256,4): cap 128 >= 64 acc + ~50.
// NOTE (R15 lesson): this is the ONLY register-feasible shape at 256 thr / 4 blocks/CU;
// any acc > 64 regs (e.g. 5x4 frags) spills through the 128-reg cap.
#define GLD(g, l) __builtin_amdgcn_global_load_lds( \
    (const __attribute__((address_space(1))) unsigned int*)(g), \
    (__attribute__((address_space(3))) unsigned int*)(l), 16, 0, 0)

__global__ __launch_bounds__(256, 4) void k_gemm_part(
    const unsigned char* __restrict__ XN, const unsigned char* __restrict__ CC,
    const float* __restrict__ wp, const float* __restrict__ bp,
    float2* __restrict__ ppart, float* __restrict__ picked2) {

  __shared__ __align__(16) char smem[32768];

  const int tid  = threadIdx.x;
  const int wave = tid >> 6, lane = tid & 63;
  const int l16  = lane & 15, lg = lane >> 4;
  const int wr   = wave >> 1, wc = wave & 1;

  // XCD swizzle: 2560 = 8 XCD x 320; a row-tile's 8 col-blocks share one XCD's L2
  const int bid = blockIdx.x;
  const int xcd = bid & 7;
  const int tt  = bid >> 3;              // 0..319
  const int rb  = xcd * 40 + (tt >> 3);  // 0..319
  const int cb  = tt & 7;                // 0..7
  const int rowbase = rb * BM;
  const int colbase = cb * BN;

  // staging source mapping (inverse of pair-packed swizzle):
  // thread t fills LDS bytes o = chunk*4096 + t*16; LDS-row R = o>>7,
  // logical_inner = (o&127) ^ ((R&7)<<4); src_row = 2R + (li>>6), src k-byte = li&63.
  const int R7   = (tid >> 3) & 7;
  const int li   = ((tid & 7) * 16) ^ (R7 << 4);
  const int row0 = 2 * (tid >> 3) + (li >> 6);   // 0..63
  const int kb   = li & 63;
  const int t16  = tid * 16;
  const unsigned char* gA = XN + (size_t)(rowbase + row0) * ROWB + kb;
  const unsigned char* gB = CC + (size_t)(colbase + row0) * ROWB + kb;

  // fragment ds_read_b128 offsets: src row r = band*64 + i*16 + l16 ->
  // LDS-row R = band*32 + i*8 + (l16>>1); logical inner = ((l16&1)<<6)|(lg<<4),
  // physical = logical ^ ((R&7)<<4)
  const int xr  = ((l16 >> 1) & 7) << 4;
  const int in0 = ((((l16 & 1) << 6) | (lg << 4)) ^ xr);
  int aoff[4], boff[4];
#pragma unroll
  for (int i = 0; i < 4; ++i) {
    aoff[i] = (wr * 32 + i * 8 + (l16 >> 1)) * 128 + in0;
    boff[i] = 8192 + (wc * 32 + i * 8 + (l16 >> 1)) * 128 + in0;
  }

  f32x4 acc[4][4];
#pragma unroll
  for (int i = 0; i < 4; ++i)
#pragma unroll
    for (int jj = 0; jj < 4; ++jj) acc[i][jj] = (f32x4){0.f, 0.f, 0.f, 0.f};

  auto STAGE = [&](int buf, int koff) {
    char* sb = smem + buf * 16384;
    GLD(gA + koff,              sb + t16);
    GLD(gA + 64 * ROWB + koff,  sb + 4096 + t16);
    GLD(gB + koff,              sb + 8192 + t16);
    GLD(gB + 64 * ROWB + koff,  sb + 12288 + t16);
  };

  STAGE(0, 0);  // prologue: tile 0

  for (int k = 0; k < KT; ++k) {
    const char* bb = smem + (k & 1) * 16384;
    if (k + 1 < KT) {
      STAGE((k + 1) & 1, (k + 1) * BKB);
      asm volatile("s_waitcnt vmcnt(4)" ::: "memory");  // tile k landed; k+1 in flight
    } else {
      asm volatile("s_waitcnt vmcnt(0)" ::: "memory");
    }
    __builtin_amdgcn_s_barrier();

    i64x2 av[4], bv[4];
#pragma unroll
    for (int i = 0; i < 4; ++i) av[i] = *(const i64x2*)(bb + aoff[i]);
#pragma unroll
    for (int jj = 0; jj < 4; ++jj) bv[jj] = *(const i64x2*)(bb + boff[jj]);
    __builtin_amdgcn_s_setprio(1);
#pragma unroll
    for (int i = 0; i < 4; ++i)
#pragma unroll
      for (int jj = 0; jj < 4; ++jj)
        acc[i][jj] = __builtin_amdgcn_mfma_f32_16x16x32_fp8_fp8(av[i][0], bv[jj][0], acc[i][jj], 0, 0, 0);
#pragma unroll
    for (int i = 0; i < 4; ++i)
#pragma unroll
      for (int jj = 0; jj < 4; ++jj)
        acc[i][jj] = __builtin_amdgcn_mfma_f32_16x16x32_fp8_fp8(av[i][1], bv[jj][1], acc[i][jj], 0, 0, 0);
    __builtin_amdgcn_s_setprio(0);
    asm volatile("s_waitcnt lgkmcnt(0)" ::: "memory");  // reads retired before overwrite
    __builtin_amdgcn_s_barrier();
  }

  // ---- epilogue: unscale + diag fixup + per-row (max, sumexp) base-2 partials ----
  const float ws2 = wp[0] * LOG2E;
  const float b2  = bp[0] * LOG2E;
  float2* red = (float2*)smem;  // [128][2] float2 = 2KB, safe after final barrier

#pragma unroll
  for (int i = 0; i < 4; ++i) {
#pragma unroll
    for (int rr = 0; rr < 4; ++rr) {
      const int lrow = wr * 64 + i * 16 + lg * 4 + rr;  // 0..127
      const int R = rowbase + lrow;
      const int n = R / M_UTT;
      float l2[4];
#pragma unroll
      for (int jj = 0; jj < 4; ++jj) {
        float sim = acc[i][jj][rr] * INV_SS;
        const int gc = colbase + wc * 64 + jj * 16 + l16;
        if (gc == n) {
          sim = (40.f * sim - 1.f) * (1.f / 39.f);  // exclusive centroid; ||xn|| = 1
          picked2[R] = fmaf(ws2, sim, b2);
        }
        l2[jj] = fmaf(ws2, sim, b2);
      }
      float mx = fmaxf(fmaxf(l2[0], l2[1]), fmaxf(l2[2], l2[3]));
#pragma unroll
      for (int d = 1; d < 16; d <<= 1) mx = fmaxf(mx, __shfl_xor(mx, d, 64));
      float s = exp2f(l2[0] - mx) + exp2f(l2[1] - mx) +
                exp2f(l2[2] - mx) + exp2f(l2[3] - mx);
#pragma unroll
      for (int d = 1; d < 16; d <<= 1) s += __shfl_xor(s, d, 64);
      if (l16 == 0) red[lrow * 2 + wc] = make_float2(mx, s);
    }
  }
  __syncthreads();
  if (tid < 128) {
    const float2 p0 = red[tid * 2 + 0];
    const float2 p1 = red[tid * 2 + 1];
    const float m2 = fmaxf(p0.x, p1.x);
    const float ss = p0.y * exp2f(p0.x - m2) + p1.y * exp2f(p1.x - m2);
    ppart[(size_t)(rowbase + tid) * 8 + cb] = make_float2(m2, ss);
  }
}

// ---------------- Kernel 3: combine partials -> row loss + per-block sum ----------------
__global__ __launch_bounds__(256) void k_combine(const float2* __restrict__ pp,
                                                 const float* __restrict__ picked2,
                                                 double* __restrict__ partial) {
  const int t = threadIdx.x;
  const int R = blockIdx.x * 256 + t;
  const float2* p = pp + (size_t)R * 8;
  float2 v[8];
#pragma unroll
  for (int j = 0; j < 8; ++j) v[j] = p[j];
  float m2 = v[0].x;
#pragma unroll
  for (int j = 1; j < 8; ++j) m2 = fmaxf(m2, v[j].x);
  float s = 0.f;
#pragma unroll
  for (int j = 0; j < 8; ++j) s += v[j].y * exp2f(v[j].x - m2);
  const float lse2 = m2 + log2f(s);
  const float rl = (lse2 - picked2[R]) * LN2;

  __shared__ double sm[256];
  sm[t] = (double)rl;
  __syncthreads();
  for (int off = 128; off > 0; off >>= 1) {
    if (t < off) sm[t] += sm[t + off];
    __syncthreads();
  }
  if (t == 0) partial[blockIdx.x] = sm[0];
}

// ---------------- Kernel 4: final mean over 160 block partials ----------------
__global__ __launch_bounds__(256) void k_reduce(const double* __restrict__ partial,
                                                float* __restrict__ out) {
  const int t = threadIdx.x;
  __shared__ double sm[256];
  sm[t] = (t < NROWS / 256) ? partial[t] : 0.0;
  __syncthreads();
  for (int off = 128; off > 0; off >>= 1) {
    if (t < off) sm[t] += sm[t + off];
    __syncthreads();
  }
  if (t == 0) out[0] = (float)(sm[0] / (double)NROWS);
}

extern "C" void kernel_launch(void* const* d_in, const int* in_sizes, int n_in,
                              void* d_out, int out_size, void* d_ws, size_t ws_size,
                              hipStream_t stream) {
  const float* x = (const float*)d_in[0];
  const float* w = (const float*)d_in[1];
  const float* b = (const float*)d_in[2];
  char* ws = (char*)d_ws;
  size_t off = 0;
  unsigned char* xn = (unsigned char*)(ws + off); off += (size_t)NROWS * D_FEAT;
  unsigned char* cc = (unsigned char*)(ws + off); off += (size_t)N_SPK * D_FEAT;
  off = (off + 255) & ~(size_t)255;
  float2* ppart   = (float2*)(ws + off); off += (size_t)NROWS * 8 * sizeof(float2);
  float* picked2  = (float*)(ws + off);  off += (size_t)NROWS * sizeof(float);
  off = (off + 255) & ~(size_t)255;
  double* partial = (double*)(ws + off); off += (size_t)(NROWS / 256) * sizeof(double);
  float* out = (float*)d_out;

  k_norm_cent<<<N_SPK, 256, 0, stream>>>(x, xn, cc);
  k_gemm_part<<<(NROWS / BM) * (N_SPK / BN), 256, 0, stream>>>(xn, cc, w, b, ppart, picked2);
  k_combine<<<NROWS / 256, 256, 0, stream>>>(ppart, picked2, partial);
  k_reduce<<<1, 256, 0, stream>>>(partial, out);
}